// Round 1
// baseline (265.316 us; speedup 1.0000x reference)
//
#include <hip/hip_runtime.h>

// out = (sum_p cos(w_p * phi_p) + (N - C)) / N,  N = next pow2 >= C.
// Pure memory-bound reduction: 256 MiB read, 4 B write.
//
// R5 theory: phi[i] and w[i] live at identical offsets in two 128 MiB
// (power-of-two-aligned) buffers -> same HBM bank, different rows. Loading
// both concurrently (R3/R4) forces per-bank row ping-pong => ~half of the
// 6.9 TB/s the fill kernel proves the machine can do. Fix: time-decouple
// the streams. Per 16 KiB phase: stage w -> LDS via global_load_lds
// (single stream), drain, then stream phi 4-deep against the LDS copy
// (single stream). 8 blocks/CU (LDS 16 KiB/block) hide phase bubbles.
// NOTE: timed dur_us carries ~170 us of harness restore/poison floor.

#define RBLOCKS 2048   // 8 blocks/CU; span = n4/2048 = 4096 v4f per array
#define RTHREADS 256
#define PHASE_V4 1024  // 16 KiB of w staged in LDS per phase

typedef float v4f __attribute__((ext_vector_type(4)));

__device__ __forceinline__ float cos4(v4f a, v4f b) {
    return __cosf(a.x * b.x) + __cosf(a.y * b.y)
         + __cosf(a.z * b.z) + __cosf(a.w * b.w);
}

__global__ __launch_bounds__(RTHREADS) void qs_partial_kernel(
    const float* __restrict__ phi, const float* __restrict__ w,
    float* __restrict__ partials, int n4, int n) {
    const v4f* __restrict__ p4 = (const v4f*)phi;
    const v4f* __restrict__ w4 = (const v4f*)w;

    __shared__ v4f wl[PHASE_V4];

    // contiguous span per block: DRAM page + XCD-L2 locality
    const int span  = (n4 + (int)gridDim.x - 1) / (int)gridDim.x;
    const int start = (int)blockIdx.x * span;
    const int lim   = (start + span < n4) ? (start + span) : n4;
    const int tid   = (int)threadIdx.x;
    // wave-uniform LDS stripe base (v4f units): global_load_lds writes
    // lane data at uniform_base + lane*16B, so each wave stages its own
    // 64-v4f stripe and reads back wl[k*256 + tid] == w4[base + k*256 + tid].
    const int wstripe = (tid >> 6) << 6;

    float acc0 = 0.0f, acc1 = 0.0f, acc2 = 0.0f, acc3 = 0.0f;

    int base = start;
    for (; base + PHASE_V4 <= lim; base += PHASE_V4) {
        // ---- W pass: single-stream global -> LDS, no VGPR roundtrip ----
        #pragma unroll
        for (int k = 0; k < 4; ++k) {
            __builtin_amdgcn_global_load_lds(
                (const __attribute__((address_space(1))) void*)
                    (w4 + base + k * 256 + tid),
                (__attribute__((address_space(3))) void*)
                    &wl[k * 256 + wstripe],
                16, 0, 0);
        }
        asm volatile("s_waitcnt vmcnt(0)" ::: "memory");
        __syncthreads();

        // ---- PHI pass: single-stream, 4-deep nt batch vs LDS w ----
        v4f a0 = __builtin_nontemporal_load(p4 + base + tid);
        v4f a1 = __builtin_nontemporal_load(p4 + base + 256 + tid);
        v4f a2 = __builtin_nontemporal_load(p4 + base + 512 + tid);
        v4f a3 = __builtin_nontemporal_load(p4 + base + 768 + tid);
        v4f b0 = wl[tid];
        v4f b1 = wl[256 + tid];
        v4f b2 = wl[512 + tid];
        v4f b3 = wl[768 + tid];
        acc0 += cos4(a0, b0);
        acc1 += cos4(a1, b1);
        acc2 += cos4(a2, b2);
        acc3 += cos4(a3, b3);
        __syncthreads();   // wl reusable next phase
    }
    // leftover float4s (span not a multiple of PHASE_V4) — paired 1-deep
    for (int i = base + tid; i < lim; i += RTHREADS) {
        v4f a = __builtin_nontemporal_load(p4 + i);
        v4f b = __builtin_nontemporal_load(w4 + i);
        acc0 += cos4(a, b);
    }
    // scalar tail (n not divisible by 4) — single thread, tiny
    if (blockIdx.x == 0 && tid == 0) {
        for (int j = n4 * 4; j < n; ++j) acc0 += __cosf(phi[j] * w[j]);
    }

    float acc = (acc0 + acc1) + (acc2 + acc3);

    // wave-64 shuffle reduce
    #pragma unroll
    for (int off = 32; off > 0; off >>= 1)
        acc += __shfl_down(acc, off, 64);

    __shared__ float smem[RTHREADS / 64];
    int lane = tid & 63;
    int wid  = tid >> 6;
    if (lane == 0) smem[wid] = acc;
    __syncthreads();
    if (tid == 0) {
        float t = 0.0f;
        #pragma unroll
        for (int k = 0; k < RTHREADS / 64; ++k) t += smem[k];
        partials[blockIdx.x] = t;
    }
}

__global__ __launch_bounds__(1024) void qs_final_kernel(
    const float* __restrict__ partials, float* __restrict__ out,
    int nb, float addend, float inv_n) {
    float acc = 0.0f;
    for (int i = threadIdx.x; i < nb; i += blockDim.x) acc += partials[i];

    #pragma unroll
    for (int off = 32; off > 0; off >>= 1)
        acc += __shfl_down(acc, off, 64);

    __shared__ float smem[1024 / 64];
    int lane = threadIdx.x & 63;
    int wid  = threadIdx.x >> 6;
    if (lane == 0) smem[wid] = acc;
    __syncthreads();
    if (threadIdx.x == 0) {
        float t = 0.0f;
        #pragma unroll
        for (int k = 0; k < 1024 / 64; ++k) t += smem[k];
        out[0] = (t + addend) * inv_n;  // overwrites poisoned d_out every call
    }
}

extern "C" void kernel_launch(void* const* d_in, const int* in_sizes, int n_in,
                              void* d_out, int out_size, void* d_ws, size_t ws_size,
                              hipStream_t stream) {
    const float* phi = (const float*)d_in[0];
    const float* w   = (const float*)d_in[1];
    float* out       = (float*)d_out;
    float* partials  = (float*)d_ws;

    int n  = in_sizes[0];
    int n4 = n >> 2;

    // N = 2^ceil(log2(n))
    long long N = 1;
    while (N < (long long)n) N <<= 1;
    float addend = (float)(N - (long long)n);
    float inv_n  = 1.0f / (float)N;

    qs_partial_kernel<<<RBLOCKS, RTHREADS, 0, stream>>>(phi, w, partials, n4, n);
    qs_final_kernel<<<1, 1024, 0, stream>>>(partials, out, RBLOCKS, addend, inv_n);
}

// Round 2
// 262.935 us; speedup vs baseline: 1.0091x; 1.0091x over previous
//
#include <hip/hip_runtime.h>

// out = (sum_p cos(w_p * phi_p) + (N - C)) / N,  N = next pow2 >= C.
// Pure memory-bound reduction: 256 MiB read, 4 B write.
//
// R6 theory: R3-R5 all used block-contiguous 64 KiB spans -> ~4096
// scattered concurrent sequential streams -> per-HBM-channel row-buffer
// thrash -> ~3.5 TB/s wall regardless of depth (R4) or stream
// decoupling (R5, refuted). Fix: classic compact grid-stride sweep
// (whole device covers one dense window at a time, like the 6.9 TB/s
// fill kernel does).
// R5's counter gift, kept deliberately: w loaded PLAIN (allocates, and
// provably stays resident in the 256 MiB L3 across iterations: R5
// FETCH_SIZE = 134 MB = phi only), phi loaded NONTEMPORAL (no-allocate,
// pure HBM stream). Demand splits ~half HBM + ~half L3 instead of
// 2x streams fighting for one path.
// NOTE: timed dur_us carries ~170 us of harness restore/poison floor.

#define RBLOCKS 2048   // 8 blocks/CU
#define RTHREADS 256

typedef float v4f __attribute__((ext_vector_type(4)));

__device__ __forceinline__ float cos4(v4f a, v4f b) {
    return __cosf(a.x * b.x) + __cosf(a.y * b.y)
         + __cosf(a.z * b.z) + __cosf(a.w * b.w);
}

__global__ __launch_bounds__(RTHREADS) void qs_partial_kernel(
    const float* __restrict__ phi, const float* __restrict__ w,
    float* __restrict__ partials, int n4, int n) {
    const v4f* __restrict__ p4 = (const v4f*)phi;
    const v4f* __restrict__ w4 = (const v4f*)w;

    const int gsz = RBLOCKS * RTHREADS;  // grid stride in v4f units
    int i = (int)blockIdx.x * RTHREADS + (int)threadIdx.x;

    float acc0 = 0.0f, acc1 = 0.0f, acc2 = 0.0f, acc3 = 0.0f;

    // 4-deep unroll across grid-stride chunks: 8 independent loads in
    // flight per lane, 4 accumulator chains. At any instant the device
    // reads 4 dense ~8 MB windows per array (row-local per channel).
    for (; i + 3 * gsz < n4; i += 4 * gsz) {
        v4f a0 = __builtin_nontemporal_load(p4 + i);
        v4f a1 = __builtin_nontemporal_load(p4 + i + gsz);
        v4f a2 = __builtin_nontemporal_load(p4 + i + 2 * gsz);
        v4f a3 = __builtin_nontemporal_load(p4 + i + 3 * gsz);
        v4f b0 = w4[i];
        v4f b1 = w4[i + gsz];
        v4f b2 = w4[i + 2 * gsz];
        v4f b3 = w4[i + 3 * gsz];
        acc0 += cos4(a0, b0);
        acc1 += cos4(a1, b1);
        acc2 += cos4(a2, b2);
        acc3 += cos4(a3, b3);
    }
    // remainder chunks (1-deep)
    for (; i < n4; i += gsz) {
        v4f a = __builtin_nontemporal_load(p4 + i);
        v4f b = w4[i];
        acc0 += cos4(a, b);
    }
    // scalar tail (n not divisible by 4) — single thread, tiny
    if (blockIdx.x == 0 && threadIdx.x == 0) {
        for (int j = n4 * 4; j < n; ++j) acc0 += __cosf(phi[j] * w[j]);
    }

    float acc = (acc0 + acc1) + (acc2 + acc3);

    // wave-64 shuffle reduce
    #pragma unroll
    for (int off = 32; off > 0; off >>= 1)
        acc += __shfl_down(acc, off, 64);

    __shared__ float smem[RTHREADS / 64];
    int lane = threadIdx.x & 63;
    int wid  = threadIdx.x >> 6;
    if (lane == 0) smem[wid] = acc;
    __syncthreads();
    if (threadIdx.x == 0) {
        float t = 0.0f;
        #pragma unroll
        for (int k = 0; k < RTHREADS / 64; ++k) t += smem[k];
        partials[blockIdx.x] = t;
    }
}

__global__ __launch_bounds__(1024) void qs_final_kernel(
    const float* __restrict__ partials, float* __restrict__ out,
    int nb, float addend, float inv_n) {
    float acc = 0.0f;
    for (int i = threadIdx.x; i < nb; i += blockDim.x) acc += partials[i];

    #pragma unroll
    for (int off = 32; off > 0; off >>= 1)
        acc += __shfl_down(acc, off, 64);

    __shared__ float smem[1024 / 64];
    int lane = threadIdx.x & 63;
    int wid  = threadIdx.x >> 6;
    if (lane == 0) smem[wid] = acc;
    __syncthreads();
    if (threadIdx.x == 0) {
        float t = 0.0f;
        #pragma unroll
        for (int k = 0; k < 1024 / 64; ++k) t += smem[k];
        out[0] = (t + addend) * inv_n;  // overwrites poisoned d_out every call
    }
}

extern "C" void kernel_launch(void* const* d_in, const int* in_sizes, int n_in,
                              void* d_out, int out_size, void* d_ws, size_t ws_size,
                              hipStream_t stream) {
    const float* phi = (const float*)d_in[0];
    const float* w   = (const float*)d_in[1];
    float* out       = (float*)d_out;
    float* partials  = (float*)d_ws;

    int n  = in_sizes[0];
    int n4 = n >> 2;

    // N = 2^ceil(log2(n))
    long long N = 1;
    while (N < (long long)n) N <<= 1;
    float addend = (float)(N - (long long)n);
    float inv_n  = 1.0f / (float)N;

    qs_partial_kernel<<<RBLOCKS, RTHREADS, 0, stream>>>(phi, w, partials, n4, n);
    qs_final_kernel<<<1, 1024, 0, stream>>>(partials, out, RBLOCKS, addend, inv_n);
}